// Round 1
// baseline (544.250 us; speedup 1.0000x reference)
//
#include <hip/hip_runtime.h>
#include <math.h>

#define WAVE 64
constexpr int   CC      = 100;    // classes
constexpr int   MAXM    = 152;    // max thresholds/class (m ~ 132; P~2621±51 -> m<=~140)
constexpr int   USTRIDE = 153;    // odd LDS stride for u table
constexpr int   BUCKET  = 4096;   // per-class positive bucket capacity
constexpr int   LCAP    = 4096;   // per-block compaction buffer (expect ~2560)
constexpr int   PAIRCAP = 640;    // rows/block = N/GRID = 512; headroom
constexpr float LSMOOTH = 0.1f;
constexpr int   TILE    = 64;     // rows per softmax tile
constexpr int   GRID    = 512;    // 2 blocks/CU x 256 CUs -> all co-resident
constexpr int   NTHR    = 256;
constexpr int   T4TILE  = TILE * CC / 4;   // 1600 float4 per tile

struct P1S {
  float  tile[2][TILE * CC];     // 51200 B double-buffered softmax tile
  float  tL[2][TILE];
  uint2  pairs[PAIRCAP];         // (class, pos-score) of this block's rows
  int    hist[CC], loc[CC], basec[CC];
  double cered[4];
  int    paircnt;
};
struct P2S {
  unsigned keys[BUCKET];
  unsigned hist[256], scan[256], sel[256];
  unsigned prefix;
  int rank, cnt_lt;
};
struct P3S {
  float umax[CC];
  uint2 buf[LCAP];
  int lcnt, gbase;
};
struct P4S {
  float us[CC * USTRIDE];        // 61200 B (union max -> 62.4KB -> 2 blocks/CU)
  int sm[CC], lcnt[CC], lsum[CC];
};
struct P5S { double r1[NTHR], r2[NTHR], r3[NTHR]; };
union SH { P1S p1; P2S p2; P3S p3; P4S p4; P5S p5; };

__device__ __forceinline__ void gload_lds16(const void* g, void* lds) {
  __builtin_amdgcn_global_load_lds(
      (const __attribute__((address_space(1))) void*)g,
      (__attribute__((address_space(3))) void*)lds, 16, 0, 0);
}

// stage one 64x100 float tile: linear LDS dest = wave-uniform base + lane*16
__device__ __forceinline__ void stage_tile(float* dst, const float4* src) {
  int t = (int)threadIdx.x;
  #pragma unroll
  for (int k = 0; k < T4TILE / NTHR; ++k) {           // 6 full rounds
    gload_lds16((const void*)(src + t), (char*)dst + (size_t)t * 16);
    t += NTHR;
  }
  if (t < T4TILE)                                     // tail: wave 0 only
    gload_lds16((const void*)(src + t), (char*)dst + (size_t)t * 16);
}

// device-wide barrier: monotone counter, absolute target = nblk*phase.
// All GRID blocks are co-resident (2/CU by LDS + launch bounds).
__device__ __forceinline__ void grid_barrier(int* bar, int phase) {
  __threadfence();
  __syncthreads();
  if (threadIdx.x == 0) {
    atomicAdd(bar, 1);
    const int target = GRID * phase;
    while (__hip_atomic_load(bar, __ATOMIC_ACQUIRE, __HIP_MEMORY_SCOPE_AGENT) < target)
      __builtin_amdgcn_s_sleep(2);
  }
  __syncthreads();
}

// branchless uniform upper_bound over sorted prefix u[0..m-1]
__device__ __forceinline__ int ubound(const float* uc, int m, float key, int maxidx) {
  int l = 0;
  #pragma unroll
  for (int s = 128; s; s >>= 1) {
    int p = l + s - 1;
    float val = uc[p < maxidx ? p : maxidx];
    l += ((p < m) && (val <= key)) ? s : 0;
  }
  return l;
}

__global__ __launch_bounds__(NTHR, 2) void mega(
    const float* __restrict__ pred, const int* __restrict__ targets,
    const float* __restrict__ weight, float* __restrict__ out,
    float* __restrict__ L_ws, double* __restrict__ ce_blk,
    float* __restrict__ u, int* __restrict__ m_arr, int* __restrict__ P_arr,
    float* __restrict__ wm_arr, int* __restrict__ zb,
    float* __restrict__ bucket, uint2* __restrict__ list,
    int list_cap, int N)
{
  __shared__ __align__(16) SH sh;
  const int tid = (int)threadIdx.x;
  const int bid = (int)blockIdx.x;
  int* cls_cnt  = zb;
  int* g_cnt    = zb + CC;
  int* g_sum    = zb + 2 * CC;
  int* list_cnt = zb + 3 * CC;
  int* bar      = zb + 3 * CC + 1;

  // ================= P1: softmax stats + CE + bucket scatter =================
  {
    const int ntiles = N / TILE;
    // issue first stage immediately, init LDS state under its latency
    stage_tile(sh.p1.tile[0], (const float4*)(pred + (size_t)bid * TILE * CC));
    for (int c2 = tid; c2 < CC; c2 += NTHR) { sh.p1.hist[c2] = 0; sh.p1.loc[c2] = 0; }
    if (tid == 0) sh.p1.paircnt = 0;

    const int x = tid & 15;            // lane within 16-wide row group
    const int G = tid >> 4;            // group 0..15 (4 rows each)
    float w[7];
    #pragma unroll
    for (int j = 0; j < 7; ++j) { int c2 = x + 16 * j; w[j] = (c2 < CC) ? weight[c2] : 0.0f; }
    float Wl = 0.0f;
    #pragma unroll
    for (int j = 0; j < 7; ++j) Wl += w[j];
    #pragma unroll
    for (int off = 1; off < 16; off <<= 1) Wl += __shfl_xor(Wl, off, 16);

    asm volatile("s_waitcnt vmcnt(0)" ::: "memory");
    __syncthreads();

    double ce_acc = 0.0;
    int it = 0;
    for (int tt = bid; tt < ntiles; tt += GRID, ++it) {
      const int cur = it & 1, nxt = cur ^ 1;
      const int ttn = tt + GRID;
      if (ttn < ntiles)   // prefetch next tile (async, overlaps compute below)
        stage_tile(sh.p1.tile[nxt], (const float4*)(pred + (size_t)ttn * TILE * CC));

      const int r0 = tt * TILE;
      #pragma unroll
      for (int rr = 0; rr < 4; ++rr) {
        const int r = G * 4 + rr;
        const float* rp = sh.p1.tile[cur] + r * CC;
        float v[7];
        #pragma unroll
        for (int j = 0; j < 7; ++j) { int c2 = x + 16 * j; v[j] = (c2 < CC) ? rp[c2] : -INFINITY; }
        float vmax = v[0];
        #pragma unroll
        for (int j = 1; j < 7; ++j) vmax = fmaxf(vmax, v[j]);
        #pragma unroll
        for (int off = 1; off < 16; off <<= 1) vmax = fmaxf(vmax, __shfl_xor(vmax, off, 16));
        float z = 0.0f, ws = 0.0f;
        #pragma unroll
        for (int j = 0; j < 7; ++j) {
          int c2 = x + 16 * j;
          if (c2 < CC) { z += __expf(v[j] - vmax); ws += w[j] * v[j]; }
        }
        #pragma unroll
        for (int off = 1; off < 16; off <<= 1) {
          z  += __shfl_xor(z,  off, 16);
          ws += __shfl_xor(ws, off, 16);
        }
        if (x == 0) {
          int tg = targets[r0 + r];
          float pt = rp[tg];
          float L = vmax + __logf(z);
          sh.p1.tL[cur][r] = L;
          float pos = pt - L;
          int slot = atomicAdd(&sh.p1.paircnt, 1);
          if (slot < PAIRCAP) {
            sh.p1.pairs[slot] = make_uint2((unsigned)tg, __float_as_uint(pos));
            atomicAdd(&sh.p1.hist[tg], 1);
          } else {  // can't happen at N=262144/GRID=512; exact fallback anyway
            int idx = atomicAdd(&cls_cnt[tg], 1);
            if (idx < BUCKET) bucket[(size_t)tg * BUCKET + idx] = pos;
          }
          ce_acc += -(double)((1.0f - LSMOOTH) * weight[tg] * (pt - L)
                              + (LSMOOTH / CC) * (ws - Wl * L));
        }
      }
      asm volatile("s_waitcnt vmcnt(0)" ::: "memory");  // next tile landed
      __syncthreads();
      if (tid < TILE) L_ws[r0 + tid] = sh.p1.tL[cur][tid];
    }

    // CE block reduce
    #pragma unroll
    for (int off = 32; off; off >>= 1) ce_acc += __shfl_xor(ce_acc, off, WAVE);
    if ((tid & 63) == 0) sh.p1.cered[tid >> 6] = ce_acc;
    // per-class global base for batch scatter
    for (int c2 = tid; c2 < CC; c2 += NTHR)
      sh.p1.basec[c2] = sh.p1.hist[c2] ? atomicAdd(&cls_cnt[c2], sh.p1.hist[c2]) : 0;
    __syncthreads();
    if (tid == 0)
      ce_blk[bid] = sh.p1.cered[0] + sh.p1.cered[1] + sh.p1.cered[2] + sh.p1.cered[3];
    const int npair = min(sh.p1.paircnt, PAIRCAP);
    for (int e = tid; e < npair; e += NTHR) {
      uint2 pr = sh.p1.pairs[e];
      int c2 = (int)pr.x;
      int idx = sh.p1.basec[c2] + atomicAdd(&sh.p1.loc[c2], 1);
      if (idx < BUCKET) bucket[(size_t)c2 * BUCKET + idx] = __uint_as_float(pr.y);
    }
  }
  grid_barrier(bar, 1);

  // ================= P2: per-class radix-select m smallest positives =========
  if (bid < CC) {
    const int c = bid;
    const int P = min(cls_cnt[c], BUCKET);
    double Kd = 0.95 * (double)P;
    int kf = (int)floor(Kd);
    int m = P - kf;
    if (m > MAXM) m = MAXM;
    if (m < 0) m = 0;
    if (tid == 0) {
      m_arr[c] = m; P_arr[c] = P;
      wm_arr[c] = (float)((double)(kf + 1) - Kd);
      sh.p2.prefix = 0; sh.p2.rank = m - 1; sh.p2.cnt_lt = 0;
    }
    for (int i = tid; i < P; i += NTHR) {
      unsigned b = __float_as_uint(bucket[(size_t)c * BUCKET + i]);
      sh.p2.keys[i] = (b & 0x80000000u) ? ~b : (b | 0x80000000u);
    }
    __syncthreads();
    if (m > 0) {
      for (int shift = 24; shift >= 0; shift -= 8) {
        sh.p2.hist[tid] = 0;
        __syncthreads();
        unsigned pref = sh.p2.prefix;
        for (int i = tid; i < P; i += NTHR) {
          unsigned k = sh.p2.keys[i];
          bool match = (shift == 24) || ((k >> (shift + 8)) == pref);
          if (match) atomicAdd(&sh.p2.hist[(k >> shift) & 255u], 1u);
        }
        __syncthreads();
        if (tid < 64) {   // single-wave inclusive scan of 256 bins
          unsigned h0 = sh.p2.hist[tid*4], h1 = sh.p2.hist[tid*4+1],
                   h2 = sh.p2.hist[tid*4+2], h3 = sh.p2.hist[tid*4+3];
          unsigned s0 = h0, s1 = s0 + h1, s2 = s1 + h2, s3 = s2 + h3;
          unsigned sc = s3;
          #pragma unroll
          for (int off = 1; off < 64; off <<= 1) {
            unsigned t2 = __shfl_up(sc, (unsigned)off, 64);
            if (tid >= off) sc += t2;
          }
          unsigned excl = sc - s3;
          sh.p2.scan[tid*4]   = excl + s0;
          sh.p2.scan[tid*4+1] = excl + s1;
          sh.p2.scan[tid*4+2] = excl + s2;
          sh.p2.scan[tid*4+3] = excl + s3;
        }
        __syncthreads();
        int r = sh.p2.rank;
        unsigned inc = sh.p2.scan[tid];
        unsigned exc = inc - sh.p2.hist[tid];
        __syncthreads();
        if ((unsigned)r >= exc && (unsigned)r < inc) {   // unique thread
          sh.p2.rank   = r - (int)exc;
          sh.p2.prefix = (pref << 8) | (unsigned)tid;
        }
        __syncthreads();
      }
      const unsigned kth = sh.p2.prefix;
      for (int i = tid; i < P; i += NTHR) {
        unsigned k = sh.p2.keys[i];
        if (k < kth) sh.p2.sel[atomicAdd(&sh.p2.cnt_lt, 1)] = k;
      }
      __syncthreads();
      const int nlt = sh.p2.cnt_lt;
      for (int j2 = nlt + tid; j2 < 256; j2 += NTHR)
        sh.p2.sel[j2] = (j2 < m) ? kth : 0xFFFFFFFFu;
      __syncthreads();
      for (int kk = 2; kk <= 256; kk <<= 1)            // bitonic 256 asc
        for (int j2 = kk >> 1; j2 > 0; j2 >>= 1) {
          int i2 = tid, ixj = tid ^ j2;
          if (ixj > i2) {
            unsigned a = sh.p2.sel[i2], b2 = sh.p2.sel[ixj];
            bool up = ((i2 & kk) == 0);
            if ((a > b2) == up) { sh.p2.sel[i2] = b2; sh.p2.sel[ixj] = a; }
          }
          __syncthreads();
        }
      if (tid < m) {
        unsigned k = sh.p2.sel[tid];
        unsigned b2 = (k & 0x80000000u) ? (k & 0x7fffffffu) : ~k;
        u[c * MAXM + tid] = __uint_as_float(b2);
      }
    }
  }
  grid_barrier(bar, 2);

  // ================= P3: stream scores, compact qualifiers ===================
  {
    if (tid < CC) {
      int m2 = m_arr[tid];
      sh.p3.umax[tid] = (m2 > 0) ? u[tid * MAXM + m2 - 1] : -INFINITY;
    }
    if (tid == 0) sh.p3.lcnt = 0;
    __syncthreads();
    const float4* pred4 = (const float4*)pred;
    const int total4 = N * (CC / 4);
    const int stride = GRID * NTHR;

    auto proc = [&](float4 v, float Ln, float4 um, int j) {
      float s0 = v.x - Ln, s1 = v.y - Ln, s2 = v.z - Ln, s3 = v.w - Ln;
      #pragma unroll
      for (int q = 0; q < 4; ++q) {
        float scv = (q == 0) ? s0 : (q == 1) ? s1 : (q == 2) ? s2 : s3;
        float mx  = (q == 0) ? um.x : (q == 1) ? um.y : (q == 2) ? um.z : um.w;
        if (scv < mx) {
          int c2 = j * 4 + q;
          int idx = atomicAdd(&sh.p3.lcnt, 1);
          if (idx < LCAP) sh.p3.buf[idx] = make_uint2((unsigned)c2, __float_as_uint(scv));
          else {  // LDS overflow: exact inline rank vs global u
            int m2 = m_arr[c2];
            int l = ubound(u + c2 * MAXM, m2, scv, MAXM - 1);
            atomicAdd(&g_cnt[c2], 1);
            atomicAdd(&g_sum[c2], m2 - 1 - l);
          }
        }
      }
    };

    int i = bid * NTHR + tid;
    while (i < total4) {
      int i2 = i + stride;
      bool has2 = (i2 < total4);
      float4 v0 = pred4[i];
      float4 v1 = has2 ? pred4[i2] : make_float4(0.f, 0.f, 0.f, 0.f);
      int n0 = i / 25, j0 = i - n0 * 25;
      float L0 = L_ws[n0];
      float4 um0 = *(const float4*)&sh.p3.umax[j0 * 4];
      proc(v0, L0, um0, j0);
      if (has2) {
        int n1 = i2 / 25, j1 = i2 - n1 * 25;
        float L1 = L_ws[n1];
        float4 um1 = *(const float4*)&sh.p3.umax[j1 * 4];
        proc(v1, L1, um1, j1);
      }
      i += 2 * stride;
    }
    __syncthreads();
    int cnt = min(sh.p3.lcnt, LCAP);
    if (tid == 0) sh.p3.gbase = atomicAdd(list_cnt, cnt);
    __syncthreads();
    const int base0 = sh.p3.gbase;
    for (int k2 = tid; k2 < cnt; k2 += NTHR) {
      int gi = base0 + k2;
      if (gi < list_cap) list[gi] = sh.p3.buf[k2];
      else {
        uint2 e = sh.p3.buf[k2];
        int c2 = (int)e.x; float scv = __uint_as_float(e.y);
        int m2 = m_arr[c2];
        int l = ubound(u + c2 * MAXM, m2, scv, MAXM - 1);
        atomicAdd(&g_cnt[c2], 1);
        atomicAdd(&g_sum[c2], m2 - 1 - l);
      }
    }
  }
  grid_barrier(bar, 3);

  // ================= P4: rank compacted entries vs LDS u-table ===============
  {
    for (int c2 = tid; c2 < CC; c2 += NTHR) {
      sh.p4.sm[c2] = m_arr[c2]; sh.p4.lcnt[c2] = 0; sh.p4.lsum[c2] = 0;
    }
    for (int t = tid; t < CC * MAXM; t += NTHR) {
      int c2 = t / MAXM, k2 = t - c2 * MAXM;
      sh.p4.us[c2 * USTRIDE + k2] = u[t];
    }
    __syncthreads();
    const int n2 = min(*list_cnt, list_cap);
    const int stride = GRID * NTHR;
    for (int idx = bid * NTHR + tid; idx < n2; idx += stride) {
      uint2 e = list[idx];
      int c2 = (int)e.x;
      float key = __uint_as_float(e.y);
      int m2 = sh.p4.sm[c2];
      int l = ubound(sh.p4.us + c2 * USTRIDE, m2, key, USTRIDE - 1);
      atomicAdd(&sh.p4.lcnt[c2], 1);
      atomicAdd(&sh.p4.lsum[c2], m2 - 1 - l);
    }
    __syncthreads();
    for (int c2 = tid; c2 < CC; c2 += NTHR)
      if (sh.p4.lcnt[c2]) {
        atomicAdd(&g_cnt[c2], sh.p4.lcnt[c2]);
        atomicAdd(&g_sum[c2], sh.p4.lsum[c2]);
      }
  }
  grid_barrier(bar, 4);

  // ================= P5: finalize (block 0) ==================================
  if (bid == 0) {
    double ce = 0.0;
    for (int i2 = tid; i2 < GRID; i2 += NTHR) ce += ce_blk[i2];
    double p = 0.0, wsum = 0.0;
    for (int c2 = tid; c2 < CC; c2 += NTHR) {
      int P = P_arr[c2], m2 = m_arr[c2];
      double wgt = (double)weight[c2];
      long long Nn = (long long)N - P;
      if (P > 0 && Nn > 0 && m2 > 0) {
        double wm = (double)wm_arr[c2];
        double S   = (double)g_sum[c2] + wm * (double)g_cnt[c2];
        double sub = 0.5 * (double)(m2 - 1) * (double)(m2 - 2) + wm * (double)(m2 - 1);
        double pc  = (S - sub) / ((double)Nn * (double)P);
        if (pc < 0.0) pc = 0.0;
        p += pc * wgt;
      }
      wsum += wgt;
    }
    sh.p5.r1[tid] = ce; sh.p5.r2[tid] = p; sh.p5.r3[tid] = wsum;
    __syncthreads();
    for (int off = NTHR >> 1; off; off >>= 1) {
      if (tid < off) {
        sh.p5.r1[tid] += sh.p5.r1[tid + off];
        sh.p5.r2[tid] += sh.p5.r2[tid + off];
        sh.p5.r3[tid] += sh.p5.r3[tid + off];
      }
      __syncthreads();
    }
    if (tid == 0) {
      double ce_loss = sh.p5.r1[0] / (double)N;
      double avg = sh.p5.r2[0] / (sh.p5.r3[0] * 0.05);   // MAX_PAUC = 0.05
      avg = fmin(fmax(avg, 0.0), 1.0);
      out[0] = (float)(0.5 * ce_loss + 0.5 * (1.0 - avg * avg));
    }
  }
}

extern "C" void kernel_launch(void* const* d_in, const int* in_sizes, int n_in,
                              void* d_out, int out_size, void* d_ws, size_t ws_size,
                              hipStream_t stream) {
  (void)n_in; (void)out_size;
  const float* pred    = (const float*)d_in[0];
  const int*   targets = (const int*)d_in[1];
  const float* weight  = (const float*)d_in[2];
  float* out = (float*)d_out;
  const int N = in_sizes[1];

  char* base = (char*)d_ws;
  size_t off = 0;
  auto take = [&](size_t bytes) {
    char* q = base + off; off += (bytes + 15) & ~(size_t)15; return q;
  };
  float*  L_ws   = (float*)take((size_t)N * 4);
  double* ce_blk = (double*)take((size_t)GRID * 8);
  float*  u      = (float*)take((size_t)CC * MAXM * 4);
  int*    m_arr  = (int*)take(CC * 4);
  int*    P_arr  = (int*)take(CC * 4);
  float*  wm_arr = (float*)take(CC * 4);
  int*    zb     = (int*)take(312 * 4);   // cls_cnt[100]|g_cnt[100]|g_sum[100]|list_cnt|bar
  float*  bucket = (float*)take((size_t)CC * BUCKET * 4);  // 1.6 MB
  uint2*  list   = (uint2*)(base + off);
  long long rem  = (long long)ws_size - (long long)off;
  int list_cap   = (rem > 0) ? (int)(rem / 8) : 0;   // expect ~1.3M entries

  hipMemsetAsync(zb, 0, 312 * 4, stream);

  int list_cap_v = list_cap;
  int N_v = N;
  mega<<<dim3(GRID), dim3(NTHR), 0, stream>>>(
      pred, targets, weight, out, L_ws, ce_blk, u, m_arr, P_arr, wm_arr,
      zb, bucket, list, list_cap_v, N_v);
}

// Round 2
// 354.228 us; speedup vs baseline: 1.5364x; 1.5364x over previous
//
#include <hip/hip_runtime.h>
#include <math.h>

#define WAVE 64
constexpr int   CC      = 100;    // classes (fixed by problem)
constexpr int   MAXM    = 160;    // max thresholds per class (~0.05*P+1 ~= 132)
constexpr int   BUCKET  = 4096;   // per-class positive-score bucket capacity (P ~ 2621 +- 51)
constexpr int   USTRIDE = 161;    // LDS stride for u table (161 mod 32 != 0 -> spread banks)
constexpr float LSMOOTH = 0.1f;
constexpr int   TILE    = 64;     // k1 rows per block
constexpr int   K3GRID  = 512;    // k3 blocks (2/CU by LDS; queued execution fine)

// ---------------- K1: LDS-tiled softmax stats (round-0 proven) ----------------
__global__ __launch_bounds__(256) void k1_tile(
    const float* __restrict__ pred, const int* __restrict__ targets,
    const float* __restrict__ weight, float* __restrict__ L_out,
    float* __restrict__ pos_out, float* __restrict__ ce_partial, int N)
{
    __shared__ float tile[TILE * CC];      // 25.6 KB
    __shared__ int   ttgt[TILE];
    __shared__ float tL[TILE], tpos[TILE];
    __shared__ float cered[4];
    const int tid = threadIdx.x;
    const int r0  = blockIdx.x * TILE;

    // stage: 64 rows x 25 float4, fully coalesced
    const float4* src = (const float4*)(pred + (size_t)r0 * CC);
    #pragma unroll
    for (int t = tid; t < TILE * (CC / 4); t += 256)
        *((float4*)&tile[t * 4]) = src[t];
    if (tid < TILE) ttgt[tid] = targets[r0 + tid];
    __syncthreads();

    const int x = tid & 15;                // lane within 16-wide row group
    const int G = tid >> 4;                // group 0..15
    float w[7];
    #pragma unroll
    for (int j = 0; j < 7; ++j) {
        int c = x + 16 * j;
        w[j] = (c < CC) ? weight[c] : 0.0f;
    }
    float Wl = 0.0f;
    #pragma unroll
    for (int j = 0; j < 7; ++j) Wl += w[j];
    #pragma unroll
    for (int off = 1; off < 16; off <<= 1) Wl += __shfl_xor(Wl, off, 16);

    float ce_acc = 0.0f;
    #pragma unroll
    for (int rr = 0; rr < 4; ++rr) {
        const int r = G * 4 + rr;
        const float* rp = tile + r * CC;
        float v[7];
        #pragma unroll
        for (int j = 0; j < 7; ++j) {
            int c = x + 16 * j;
            v[j] = (c < CC) ? rp[c] : -INFINITY;
        }
        float vmax = v[0];
        #pragma unroll
        for (int j = 1; j < 7; ++j) vmax = fmaxf(vmax, v[j]);
        #pragma unroll
        for (int off = 1; off < 16; off <<= 1) vmax = fmaxf(vmax, __shfl_xor(vmax, off, 16));
        float z = 0.0f, ws = 0.0f;
        #pragma unroll
        for (int j = 0; j < 7; ++j) {
            int c = x + 16 * j;
            if (c < CC) { z += __expf(v[j] - vmax); ws += w[j] * v[j]; }
        }
        #pragma unroll
        for (int off = 1; off < 16; off <<= 1) {
            z  += __shfl_xor(z,  off, 16);
            ws += __shfl_xor(ws, off, 16);
        }
        float L = vmax + __logf(z);
        if (x == 0) {
            int t = ttgt[r];
            float pt = rp[t];
            tL[r] = L; tpos[r] = pt - L;
            ce_acc += -((1.0f - LSMOOTH) * weight[t] * (pt - L)
                        + (LSMOOTH / CC) * (ws - Wl * L));
        }
    }
    #pragma unroll
    for (int off = 32; off; off >>= 1) ce_acc += __shfl_xor(ce_acc, off, WAVE);
    if ((tid & 63) == 0) cered[tid >> 6] = ce_acc;
    __syncthreads();
    if (tid < TILE) {                          // coalesced output
        L_out[r0 + tid]   = tL[tid];
        pos_out[r0 + tid] = tpos[tid];
    }
    if (tid == 0)
        ce_partial[blockIdx.x] = cered[0] + cered[1] + cered[2] + cered[3];
}

// ------- K1b: counting scatter of positive scores into per-class buckets -------
__global__ __launch_bounds__(256) void k1b_scatter(
    const int* __restrict__ targets, const float* __restrict__ pos,
    int* __restrict__ cls_cnt, float* __restrict__ bucket, int N)
{
    __shared__ int hist[CC];
    __shared__ int base[CC];
    __shared__ int loc[CC];
    const int tid = threadIdx.x;
    const int rowsPerBlock = N / gridDim.x;
    const int r0 = blockIdx.x * rowsPerBlock;
    const int r1 = r0 + rowsPerBlock;
    for (int c = tid; c < CC; c += blockDim.x) { hist[c] = 0; loc[c] = 0; }
    __syncthreads();
    for (int r = r0 + tid; r < r1; r += blockDim.x)
        atomicAdd(&hist[targets[r]], 1);
    __syncthreads();
    for (int c = tid; c < CC; c += blockDim.x)
        base[c] = (hist[c] > 0) ? atomicAdd(&cls_cnt[c], hist[c]) : 0;
    __syncthreads();
    for (int r = r0 + tid; r < r1; r += blockDim.x) {
        int c = targets[r];
        int idx = base[c] + atomicAdd(&loc[c], 1);
        if (idx < BUCKET) bucket[(size_t)c * BUCKET + idx] = pos[r];
    }
}

// --------- K2: per class, radix-select the m smallest positive scores ---------
// (round-0 proven, with round-1's verified single-wave shfl scan replacing
//  the 16-sync Hillis-Steele per radix round)
__global__ __launch_bounds__(256) void k2_select(
    const float* __restrict__ bucket, const int* __restrict__ cls_cnt,
    float* __restrict__ u, int* __restrict__ m_arr, int* __restrict__ P_arr,
    float* __restrict__ wm_arr)
{
    __shared__ unsigned int keys[BUCKET];     // 16 KB
    __shared__ unsigned int hist[256];
    __shared__ unsigned int scan[256];
    __shared__ unsigned int sel[256];
    __shared__ unsigned int s_prefix;
    __shared__ int s_rank;
    __shared__ int cnt_lt;
    const int c   = blockIdx.x;
    const int tid = threadIdx.x;
    const int P = min(cls_cnt[c], BUCKET);
    double Kd = 0.95 * (double)P;
    int kf = (int)floor(Kd);
    int m = P - kf;
    if (m > MAXM) m = MAXM;
    if (m < 0) m = 0;
    if (tid == 0) {
        m_arr[c] = m; P_arr[c] = P;
        wm_arr[c] = (float)((double)(kf + 1) - Kd);   // fractional last-step weight
        s_prefix = 0; s_rank = m - 1; cnt_lt = 0;
    }
    // monotone float->uint key
    for (int i = tid; i < P; i += 256) {
        unsigned int b = __float_as_uint(bucket[(size_t)c * BUCKET + i]);
        keys[i] = (b & 0x80000000u) ? ~b : (b | 0x80000000u);
    }
    __syncthreads();
    if (m == 0) return;                                // uniform exit

    // 4 rounds of 8-bit MSB radix select
    for (int shift = 24; shift >= 0; shift -= 8) {
        hist[tid] = 0;
        __syncthreads();
        unsigned int pref = s_prefix;
        for (int i = tid; i < P; i += 256) {
            unsigned int k = keys[i];
            bool match = (shift == 24) || ((k >> (shift + 8)) == pref);
            if (match) atomicAdd(&hist[(k >> shift) & 255u], 1u);
        }
        __syncthreads();
        if (tid < 64) {   // single-wave inclusive scan of 256 bins (verified r1)
            unsigned h0 = hist[tid*4], h1 = hist[tid*4+1],
                     h2 = hist[tid*4+2], h3 = hist[tid*4+3];
            unsigned s0 = h0, s1 = s0 + h1, s2 = s1 + h2, s3 = s2 + h3;
            unsigned sc = s3;
            #pragma unroll
            for (int off = 1; off < 64; off <<= 1) {
                unsigned t2 = __shfl_up(sc, (unsigned)off, 64);
                if (tid >= off) sc += t2;
            }
            unsigned excl = sc - s3;
            scan[tid*4]   = excl + s0;
            scan[tid*4+1] = excl + s1;
            scan[tid*4+2] = excl + s2;
            scan[tid*4+3] = excl + s3;
        }
        __syncthreads();
        int r = s_rank;
        unsigned int inc = scan[tid];
        unsigned int exc = inc - hist[tid];
        __syncthreads();
        if ((unsigned int)r >= exc && (unsigned int)r < inc) {   // unique thread
            s_rank   = r - (int)exc;
            s_prefix = (pref << 8) | (unsigned int)tid;
        }
        __syncthreads();
    }
    const unsigned int kth = s_prefix;

    // collect strictly-less keys, fill ties, pad to 256
    for (int i = tid; i < P; i += 256) {
        unsigned int k = keys[i];
        if (k < kth) {
            int pslot = atomicAdd(&cnt_lt, 1);
            sel[pslot] = k;
        }
    }
    __syncthreads();
    const int nlt = cnt_lt;
    for (int j = nlt + tid; j < 256; j += 256) sel[j] = (j < m) ? kth : 0xFFFFFFFFu;
    __syncthreads();
    // bitonic sort 256 ascending
    for (int kk = 2; kk <= 256; kk <<= 1) {
        for (int j = kk >> 1; j > 0; j >>= 1) {
            int i = tid, ixj = tid ^ j;
            if (ixj > i) {
                unsigned int a = sel[i], b = sel[ixj];
                bool up = ((i & kk) == 0);
                if ((a > b) == up) { sel[i] = b; sel[ixj] = a; }
            }
            __syncthreads();
        }
    }
    if (tid < m) {
        unsigned int k = sel[tid];
        unsigned int b = (k & 0x80000000u) ? (k & 0x7fffffffu) : ~k;
        u[c * MAXM + tid] = __uint_as_float(b);        // m smallest, ascending
    }
}

// branchless uniform upper_bound over sorted prefix u[0..m-1]
__device__ __forceinline__ int ubound(const float* uc, int m, float key, int maxidx) {
    int l = 0;
    #pragma unroll
    for (int s = 128; s; s >>= 1) {
        int p = l + s - 1;
        float val = uc[p < maxidx ? p : maxidx];
        l += ((p < m) && (val <= key)) ? s : 0;
    }
    return l;
}

// --------- K3 (fused k3a+k3b+k4): stream scores, rank directly vs LDS u-table,
//           block-aggregate, last block finalizes. No global list round-trip. ---------
__global__ __launch_bounds__(256) void k3_rank_final(
    const float4* __restrict__ pred4, const float* __restrict__ L,
    const float* __restrict__ u, const int* __restrict__ m_arr,
    const int* __restrict__ P_arr, const float* __restrict__ wm_arr,
    const float* __restrict__ weight, const float* __restrict__ ce_partial,
    int nPartial, int* __restrict__ g_cnt, int* __restrict__ g_sum,
    int* __restrict__ done, float* __restrict__ out, int N)
{
    __shared__ float us[CC * USTRIDE];         // 64.4 KB, stride 161 spreads banks
    __shared__ float umax_s[CC];
    __shared__ int   sm[CC], lcnt[CC], lsum[CC];
    __shared__ int   lastflag;
    __shared__ double r1[256], r2[256], r3[256];   // finalize scratch (6 KB)
    const int tid = threadIdx.x;

    for (int c = tid; c < CC; c += 256) {
        int m = m_arr[c];
        sm[c] = m; lcnt[c] = 0; lsum[c] = 0;
        umax_s[c] = (m > 0) ? u[c * MAXM + m - 1] : -INFINITY;
    }
    for (int t = tid; t < CC * MAXM; t += 256) {
        int c = t / MAXM, k = t - c * MAXM;
        us[c * USTRIDE + k] = u[t];
    }
    __syncthreads();

    const int total4 = N * (CC / 4);
    const int stride = K3GRID * 256;           // 131072; total4/stride = 50 exactly

    auto proc = [&](float4 v, float Ln, int j) {
        float4 um = *((const float4*)&umax_s[j * 4]);
        float s0 = v.x - Ln, s1 = v.y - Ln, s2 = v.z - Ln, s3 = v.w - Ln;
        #pragma unroll
        for (int q = 0; q < 4; ++q) {
            float scv = (q == 0) ? s0 : (q == 1) ? s1 : (q == 2) ? s2 : s3;
            float mx  = (q == 0) ? um.x : (q == 1) ? um.y : (q == 2) ? um.z : um.w;
            if (scv < mx) {
                int c = j * 4 + q;
                int m = sm[c];
                int l = ubound(us + c * USTRIDE, m, scv, USTRIDE - 1);
                atomicAdd(&lcnt[c], 1);
                atomicAdd(&lsum[c], m - 1 - l);
            }
        }
    };

    int i = blockIdx.x * 256 + tid;
    while (i < total4) {                       // 4-deep load ILP
        const int ia = i + stride, ib = i + 2 * stride, ic = i + 3 * stride;
        const bool ha = ia < total4, hb = ib < total4, hc = ic < total4;
        float4 v0 = pred4[i];
        float4 va = ha ? pred4[ia] : make_float4(0.f, 0.f, 0.f, 0.f);
        float4 vb = hb ? pred4[ib] : make_float4(0.f, 0.f, 0.f, 0.f);
        float4 vc = hc ? pred4[ic] : make_float4(0.f, 0.f, 0.f, 0.f);
        int n0 = i / 25,  j0 = i - n0 * 25;
        float L0 = L[n0];
        int na = 0, ja = 0, nb = 0, jb = 0, nc = 0, jc = 0;
        float La = 0.f, Lb = 0.f, Lc = 0.f;
        if (ha) { na = ia / 25; ja = ia - na * 25; La = L[na]; }
        if (hb) { nb = ib / 25; jb = ib - nb * 25; Lb = L[nb]; }
        if (hc) { nc = ic / 25; jc = ic - nc * 25; Lc = L[nc]; }
        proc(v0, L0, j0);
        if (ha) proc(va, La, ja);
        if (hb) proc(vb, Lb, jb);
        if (hc) proc(vc, Lc, jc);
        i += 4 * stride;
    }
    __syncthreads();

    for (int c = tid; c < CC; c += 256)
        if (lcnt[c]) {
            atomicAdd(&g_cnt[c], lcnt[c]);
            atomicAdd(&g_sum[c], lsum[c]);
        }
    __threadfence();                           // drain this thread's atomics
    __syncthreads();
    if (tid == 0) {
        int r = atomicAdd(done, 1);
        lastflag = (r == (int)gridDim.x - 1) ? 1 : 0;
    }
    __syncthreads();
    if (!lastflag) return;

    // ---------------- finalize (identical math to round-0 k4) ----------------
    double ce = 0.0;
    for (int t = tid; t < nPartial; t += 256) ce += (double)ce_partial[t];
    double p = 0.0, wsum = 0.0;
    for (int c = tid; c < CC; c += 256) {
        int P = P_arr[c], m = m_arr[c];
        double wgt = (double)weight[c];
        long long Nn = (long long)N - P;
        if (P > 0 && Nn > 0 && m > 0) {
            int gc = __hip_atomic_load(&g_cnt[c], __ATOMIC_RELAXED, __HIP_MEMORY_SCOPE_AGENT);
            int gs = __hip_atomic_load(&g_sum[c], __ATOMIC_RELAXED, __HIP_MEMORY_SCOPE_AGENT);
            double wm = (double)wm_arr[c];
            double S   = (double)gs + wm * (double)gc;
            double sub = 0.5 * (double)(m - 1) * (double)(m - 2) + wm * (double)(m - 1);
            double pc  = (S - sub) / ((double)Nn * (double)P);
            if (pc < 0.0) pc = 0.0;
            p += pc * wgt;
        }
        wsum += wgt;
    }
    r1[tid] = ce; r2[tid] = p; r3[tid] = wsum;
    __syncthreads();
    for (int off = 128; off; off >>= 1) {
        if (tid < off) {
            r1[tid] += r1[tid + off];
            r2[tid] += r2[tid + off];
            r3[tid] += r3[tid + off];
        }
        __syncthreads();
    }
    if (tid == 0) {
        double ce_loss = r1[0] / (double)N;
        double avg = r2[0] / (r3[0] * 0.05);           // MAX_PAUC = R1-R0 = 0.05
        avg = fmin(fmax(avg, 0.0), 1.0);
        out[0] = (float)(0.5 * ce_loss + 0.5 * (1.0 - avg * avg));
    }
}

extern "C" void kernel_launch(void* const* d_in, const int* in_sizes, int n_in,
                              void* d_out, int out_size, void* d_ws, size_t ws_size,
                              hipStream_t stream) {
    (void)n_in; (void)out_size; (void)ws_size;
    const float* pred    = (const float*)d_in[0];
    const int*   targets = (const int*)d_in[1];
    const float* weight  = (const float*)d_in[2];
    float* out = (float*)d_out;
    const int N = in_sizes[1];

    const int K1_BLOCKS = N / TILE;                    // 4096
    char* base = (char*)d_ws;
    size_t off = 0;
    auto take = [&](size_t bytes) { char* q = base + off; off += (bytes + 15) & ~(size_t)15; return q; };
    float* L_ws       = (float*)take((size_t)N * 4);
    float* pos_ws     = (float*)take((size_t)N * 4);
    float* ce_partial = (float*)take((size_t)K1_BLOCKS * 4);
    float* u          = (float*)take((size_t)CC * MAXM * 4);
    int*   m_arr      = (int*)take(CC * 4);
    int*   P_arr      = (int*)take(CC * 4);
    float* wm_arr     = (float*)take(CC * 4);
    int*   zero_blk   = (int*)take(304 * 4);           // cls_cnt|g_cnt|g_sum|done
    int*   cls_cnt  = zero_blk;
    int*   g_cnt    = zero_blk + CC;
    int*   g_sum    = zero_blk + 2 * CC;
    int*   done     = zero_blk + 3 * CC;
    float* bucket     = (float*)take((size_t)CC * BUCKET * 4);   // 1.6 MB

    hipMemsetAsync(zero_blk, 0, 304 * 4, stream);

    k1_tile<<<K1_BLOCKS, 256, 0, stream>>>(pred, targets, weight, L_ws, pos_ws,
                                           ce_partial, N);
    k1b_scatter<<<256, 256, 0, stream>>>(targets, pos_ws, cls_cnt, bucket, N);
    k2_select<<<CC, 256, 0, stream>>>(bucket, cls_cnt, u, m_arr, P_arr, wm_arr);
    k3_rank_final<<<K3GRID, 256, 0, stream>>>((const float4*)pred, L_ws, u, m_arr,
                                              P_arr, wm_arr, weight, ce_partial,
                                              K1_BLOCKS, g_cnt, g_sum, done, out, N);
}

// Round 3
// 281.422 us; speedup vs baseline: 1.9339x; 1.2587x over previous
//
#include <hip/hip_runtime.h>
#include <math.h>

#define WAVE 64
constexpr int   CC      = 100;    // classes (fixed by problem)
constexpr int   MAXM    = 160;    // max thresholds per class (~0.05*P+1 ~= 132)
constexpr int   BUCKET  = 4096;   // per-class positive-score bucket capacity (P ~ 2621 +- 51)
constexpr int   USTRIDE = 161;    // LDS stride for u table (161 mod 32 != 0 -> spread banks)
constexpr int   LCAP    = 4096;   // per-block LDS compaction buffer (expected ~1300)
constexpr float LSMOOTH = 0.1f;
constexpr int   TILE    = 64;     // k1 rows per block
constexpr int   K3AGRID = 1024;
constexpr int   K3BGRID = 512;

// ---------------- K1: LDS-tiled softmax stats (round-0 proven) ----------------
__global__ __launch_bounds__(256) void k1_tile(
    const float* __restrict__ pred, const int* __restrict__ targets,
    const float* __restrict__ weight, float* __restrict__ L_out,
    float* __restrict__ pos_out, float* __restrict__ ce_partial, int N)
{
    __shared__ float tile[TILE * CC];      // 25.6 KB
    __shared__ int   ttgt[TILE];
    __shared__ float tL[TILE], tpos[TILE];
    __shared__ float cered[4];
    const int tid = threadIdx.x;
    const int r0  = blockIdx.x * TILE;

    const float4* src = (const float4*)(pred + (size_t)r0 * CC);
    #pragma unroll
    for (int t = tid; t < TILE * (CC / 4); t += 256)
        *((float4*)&tile[t * 4]) = src[t];
    if (tid < TILE) ttgt[tid] = targets[r0 + tid];
    __syncthreads();

    const int x = tid & 15;                // lane within 16-wide row group
    const int G = tid >> 4;                // group 0..15
    float w[7];
    #pragma unroll
    for (int j = 0; j < 7; ++j) {
        int c = x + 16 * j;
        w[j] = (c < CC) ? weight[c] : 0.0f;
    }
    float Wl = 0.0f;
    #pragma unroll
    for (int j = 0; j < 7; ++j) Wl += w[j];
    #pragma unroll
    for (int off = 1; off < 16; off <<= 1) Wl += __shfl_xor(Wl, off, 16);

    float ce_acc = 0.0f;
    #pragma unroll
    for (int rr = 0; rr < 4; ++rr) {
        const int r = G * 4 + rr;
        const float* rp = tile + r * CC;
        float v[7];
        #pragma unroll
        for (int j = 0; j < 7; ++j) {
            int c = x + 16 * j;
            v[j] = (c < CC) ? rp[c] : -INFINITY;
        }
        float vmax = v[0];
        #pragma unroll
        for (int j = 1; j < 7; ++j) vmax = fmaxf(vmax, v[j]);
        #pragma unroll
        for (int off = 1; off < 16; off <<= 1) vmax = fmaxf(vmax, __shfl_xor(vmax, off, 16));
        float z = 0.0f, ws = 0.0f;
        #pragma unroll
        for (int j = 0; j < 7; ++j) {
            int c = x + 16 * j;
            if (c < CC) { z += __expf(v[j] - vmax); ws += w[j] * v[j]; }
        }
        #pragma unroll
        for (int off = 1; off < 16; off <<= 1) {
            z  += __shfl_xor(z,  off, 16);
            ws += __shfl_xor(ws, off, 16);
        }
        float L = vmax + __logf(z);
        if (x == 0) {
            int t = ttgt[r];
            float pt = rp[t];
            tL[r] = L; tpos[r] = pt - L;
            ce_acc += -((1.0f - LSMOOTH) * weight[t] * (pt - L)
                        + (LSMOOTH / CC) * (ws - Wl * L));
        }
    }
    #pragma unroll
    for (int off = 32; off; off >>= 1) ce_acc += __shfl_xor(ce_acc, off, WAVE);
    if ((tid & 63) == 0) cered[tid >> 6] = ce_acc;
    __syncthreads();
    if (tid < TILE) {
        L_out[r0 + tid]   = tL[tid];
        pos_out[r0 + tid] = tpos[tid];
    }
    if (tid == 0)
        ce_partial[blockIdx.x] = cered[0] + cered[1] + cered[2] + cered[3];
}

// ------- K1b: counting scatter of positive scores into per-class buckets -------
__global__ __launch_bounds__(256) void k1b_scatter(
    const int* __restrict__ targets, const float* __restrict__ pos,
    int* __restrict__ cls_cnt, float* __restrict__ bucket, int N)
{
    __shared__ int hist[CC];
    __shared__ int base[CC];
    __shared__ int loc[CC];
    const int tid = threadIdx.x;
    const int rowsPerBlock = N / gridDim.x;
    const int r0 = blockIdx.x * rowsPerBlock;
    const int r1 = r0 + rowsPerBlock;
    for (int c = tid; c < CC; c += blockDim.x) { hist[c] = 0; loc[c] = 0; }
    __syncthreads();
    for (int r = r0 + tid; r < r1; r += blockDim.x)
        atomicAdd(&hist[targets[r]], 1);
    __syncthreads();
    for (int c = tid; c < CC; c += blockDim.x)
        base[c] = (hist[c] > 0) ? atomicAdd(&cls_cnt[c], hist[c]) : 0;
    __syncthreads();
    for (int r = r0 + tid; r < r1; r += blockDim.x) {
        int c = targets[r];
        int idx = base[c] + atomicAdd(&loc[c], 1);
        if (idx < BUCKET) bucket[(size_t)c * BUCKET + idx] = pos[r];
    }
}

// --------- K2: per class, radix-select the m smallest positive scores ---------
__global__ __launch_bounds__(256) void k2_select(
    const float* __restrict__ bucket, const int* __restrict__ cls_cnt,
    float* __restrict__ u, int* __restrict__ m_arr, int* __restrict__ P_arr,
    float* __restrict__ wm_arr)
{
    __shared__ unsigned int keys[BUCKET];     // 16 KB
    __shared__ unsigned int hist[256];
    __shared__ unsigned int scan[256];
    __shared__ unsigned int sel[256];
    __shared__ unsigned int s_prefix;
    __shared__ int s_rank;
    __shared__ int cnt_lt;
    const int c   = blockIdx.x;
    const int tid = threadIdx.x;
    const int P = min(cls_cnt[c], BUCKET);
    double Kd = 0.95 * (double)P;
    int kf = (int)floor(Kd);
    int m = P - kf;
    if (m > MAXM) m = MAXM;
    if (m < 0) m = 0;
    if (tid == 0) {
        m_arr[c] = m; P_arr[c] = P;
        wm_arr[c] = (float)((double)(kf + 1) - Kd);   // fractional last-step weight
        s_prefix = 0; s_rank = m - 1; cnt_lt = 0;
    }
    for (int i = tid; i < P; i += 256) {
        unsigned int b = __float_as_uint(bucket[(size_t)c * BUCKET + i]);
        keys[i] = (b & 0x80000000u) ? ~b : (b | 0x80000000u);
    }
    __syncthreads();
    if (m == 0) return;

    for (int shift = 24; shift >= 0; shift -= 8) {
        hist[tid] = 0;
        __syncthreads();
        unsigned int pref = s_prefix;
        for (int i = tid; i < P; i += 256) {
            unsigned int k = keys[i];
            bool match = (shift == 24) || ((k >> (shift + 8)) == pref);
            if (match) atomicAdd(&hist[(k >> shift) & 255u], 1u);
        }
        __syncthreads();
        if (tid < 64) {   // single-wave inclusive scan of 256 bins (verified r1)
            unsigned h0 = hist[tid*4], h1 = hist[tid*4+1],
                     h2 = hist[tid*4+2], h3 = hist[tid*4+3];
            unsigned s0 = h0, s1 = s0 + h1, s2 = s1 + h2, s3 = s2 + h3;
            unsigned sc = s3;
            #pragma unroll
            for (int off = 1; off < 64; off <<= 1) {
                unsigned t2 = __shfl_up(sc, (unsigned)off, 64);
                if (tid >= off) sc += t2;
            }
            unsigned excl = sc - s3;
            scan[tid*4]   = excl + s0;
            scan[tid*4+1] = excl + s1;
            scan[tid*4+2] = excl + s2;
            scan[tid*4+3] = excl + s3;
        }
        __syncthreads();
        int r = s_rank;
        unsigned int inc = scan[tid];
        unsigned int exc = inc - hist[tid];
        __syncthreads();
        if ((unsigned int)r >= exc && (unsigned int)r < inc) {   // unique thread
            s_rank   = r - (int)exc;
            s_prefix = (pref << 8) | (unsigned int)tid;
        }
        __syncthreads();
    }
    const unsigned int kth = s_prefix;

    for (int i = tid; i < P; i += 256) {
        unsigned int k = keys[i];
        if (k < kth) {
            int pslot = atomicAdd(&cnt_lt, 1);
            sel[pslot] = k;
        }
    }
    __syncthreads();
    const int nlt = cnt_lt;
    for (int j = nlt + tid; j < 256; j += 256) sel[j] = (j < m) ? kth : 0xFFFFFFFFu;
    __syncthreads();
    for (int kk = 2; kk <= 256; kk <<= 1) {
        for (int j = kk >> 1; j > 0; j >>= 1) {
            int i = tid, ixj = tid ^ j;
            if (ixj > i) {
                unsigned int a = sel[i], b = sel[ixj];
                bool up = ((i & kk) == 0);
                if ((a > b) == up) { sel[i] = b; sel[ixj] = a; }
            }
            __syncthreads();
        }
    }
    if (tid < m) {
        unsigned int k = sel[tid];
        unsigned int b = (k & 0x80000000u) ? (k & 0x7fffffffu) : ~k;
        u[c * MAXM + tid] = __uint_as_float(b);        // m smallest, ascending
    }
}

// branchless uniform upper_bound over sorted prefix u[0..m-1]
__device__ __forceinline__ int ubound(const float* uc, int m, float key, int maxidx) {
    int l = 0;
    #pragma unroll
    for (int s = 128; s; s >>= 1) {
        int p = l + s - 1;
        float val = uc[p < maxidx ? p : maxidx];
        l += ((p < m) && (val <= key)) ? s : 0;
    }
    return l;
}

// --------- K3a: stream scores, wave-aggregated compaction of qualifiers ---------
// Small LDS (no u-table) -> 4 blocks/CU, 16 waves. Dense searches happen in k3b.
__global__ __launch_bounds__(256) void k3a_stream(
    const float4* __restrict__ pred4, const float* __restrict__ L,
    const float* __restrict__ u, const int* __restrict__ m_arr,
    uint2* __restrict__ list, int* __restrict__ list_cnt, int list_cap,
    int* __restrict__ g_cnt, int* __restrict__ g_sum, int total4)
{
    __shared__ float umax_s[CC];
    __shared__ uint2 buf[LCAP];               // 32 KB
    __shared__ int lcnt;
    __shared__ int gbase;
    const int tid  = threadIdx.x;
    const int lane = tid & 63;
    if (tid < CC) {
        int m = m_arr[tid];
        umax_s[tid] = (m > 0) ? u[tid * MAXM + m - 1] : -INFINITY;
    }
    if (tid == 0) lcnt = 0;
    __syncthreads();

    // wave-aggregated push: one LDS atomic per wave per sub-block
    auto pushq = [&](bool qual, int c, float sc) {
        unsigned long long mask = __ballot(qual);
        if (mask == 0ull) return;
        int lead = __ffsll((long long)mask) - 1;
        int nq   = __popcll(mask);
        int base = 0;
        if (lane == lead) base = atomicAdd(&lcnt, nq);
        base = __shfl(base, lead);
        if (qual) {
            int my  = __popcll(mask & ((1ull << lane) - 1ull));
            int idx = base + my;
            if (idx < LCAP) {
                buf[idx] = make_uint2((unsigned int)c, __float_as_uint(sc));
            } else {                           // LDS overflow: inline exact rank
                int m = m_arr[c];
                int l = ubound(u + c * MAXM, m, sc, MAXM - 1);
                atomicAdd(&g_cnt[c], 1);
                atomicAdd(&g_sum[c], m - 1 - l);
            }
        }
    };

    auto proc = [&](float4 v, float Ln, int j) {
        float4 um = *((const float4*)&umax_s[j * 4]);
        pushq(v.x - Ln < um.x, j * 4 + 0, v.x - Ln);
        pushq(v.y - Ln < um.y, j * 4 + 1, v.y - Ln);
        pushq(v.z - Ln < um.z, j * 4 + 2, v.z - Ln);
        pushq(v.w - Ln < um.w, j * 4 + 3, v.w - Ln);
    };

    const int stride = K3AGRID * 256;          // 262144; total4/stride = 25 exactly
    int i = blockIdx.x * 256 + tid;
    while (i < total4) {                       // 4-deep load ILP
        const int ia = i + stride, ib = i + 2 * stride, ic = i + 3 * stride;
        const bool ha = ia < total4, hb = ib < total4, hc = ic < total4;
        float4 v0 = pred4[i];
        float4 va = ha ? pred4[ia] : make_float4(0.f, 0.f, 0.f, 0.f);
        float4 vb = hb ? pred4[ib] : make_float4(0.f, 0.f, 0.f, 0.f);
        float4 vc = hc ? pred4[ic] : make_float4(0.f, 0.f, 0.f, 0.f);
        int n0 = i / 25, j0 = i - n0 * 25;
        float L0 = L[n0];
        proc(v0, L0, j0);
        if (ha) { int na = ia / 25, ja = ia - na * 25; proc(va, L[na], ja); }
        if (hb) { int nb = ib / 25, jb = ib - nb * 25; proc(vb, L[nb], jb); }
        if (hc) { int nc = ic / 25, jc = ic - nc * 25; proc(vc, L[nc], jc); }
        i += 4 * stride;
    }
    __syncthreads();
    int cnt = min(lcnt, LCAP);
    if (tid == 0) gbase = atomicAdd(list_cnt, cnt);
    __syncthreads();
    const int base0 = gbase;
    for (int k = tid; k < cnt; k += 256) {
        int gi = base0 + k;
        if (gi < list_cap) {
            list[gi] = buf[k];
        } else {                               // global overflow: inline exact
            uint2 e = buf[k];
            int c = (int)e.x; float sc = __uint_as_float(e.y);
            int m = m_arr[c];
            int l = ubound(u + c * MAXM, m, sc, MAXM - 1);
            atomicAdd(&g_cnt[c], 1);
            atomicAdd(&g_sum[c], m - 1 - l);
        }
    }
}

// --------- K3b: dense rank vs LDS u-table (4-way interleaved searches) + finalize ---------
__global__ __launch_bounds__(256) void k3b_rank_final(
    const uint2* __restrict__ list, const int* __restrict__ list_cnt, int list_cap,
    const float* __restrict__ u, const int* __restrict__ m_arr,
    const int* __restrict__ P_arr, const float* __restrict__ wm_arr,
    const float* __restrict__ weight, const float* __restrict__ ce_partial,
    int nPartial, int* __restrict__ g_cnt, int* __restrict__ g_sum,
    int* __restrict__ done, float* __restrict__ out, int N)
{
    __shared__ float us[CC * USTRIDE];         // 64.4 KB
    __shared__ int sm[CC], lcnt[CC], lsum[CC];
    __shared__ int lastflag;
    __shared__ double r1[256], r2[256], r3[256];
    const int tid = threadIdx.x;
    for (int c = tid; c < CC; c += 256) { sm[c] = m_arr[c]; lcnt[c] = 0; lsum[c] = 0; }
    for (int t = tid; t < CC * MAXM; t += 256) {
        int c = t / MAXM, k = t - c * MAXM;
        us[c * USTRIDE + k] = u[t];
    }
    __syncthreads();
    const int n = min(*list_cnt, list_cap);
    const int stride = K3BGRID * 256;
    for (int base = blockIdx.x * 256 + tid; base < n; base += 4 * stride) {
        int  cc4[4]; int mm4[4]; float kk4[4]; bool hh4[4];
        #pragma unroll
        for (int t = 0; t < 4; ++t) {
            int idx = base + t * stride;
            bool h = idx < n;
            uint2 e = h ? list[idx] : make_uint2(0u, 0u);
            hh4[t] = h;
            cc4[t] = (int)e.x;
            mm4[t] = h ? sm[(int)e.x] : 0;
            kk4[t] = __uint_as_float(e.y);
        }
        int ll4[4] = {0, 0, 0, 0};
        #pragma unroll
        for (int s = 128; s; s >>= 1) {        // 4 independent chains stepped together
            #pragma unroll
            for (int t = 0; t < 4; ++t) {
                int p = ll4[t] + s - 1;
                float val = us[cc4[t] * USTRIDE + (p < USTRIDE - 1 ? p : USTRIDE - 1)];
                ll4[t] += ((p < mm4[t]) && (val <= kk4[t])) ? s : 0;
            }
        }
        #pragma unroll
        for (int t = 0; t < 4; ++t)
            if (hh4[t]) {
                atomicAdd(&lcnt[cc4[t]], 1);
                atomicAdd(&lsum[cc4[t]], mm4[t] - 1 - ll4[t]);
            }
    }
    __syncthreads();
    for (int c = tid; c < CC; c += 256)
        if (lcnt[c]) { atomicAdd(&g_cnt[c], lcnt[c]); atomicAdd(&g_sum[c], lsum[c]); }
    __threadfence();
    __syncthreads();
    if (tid == 0) {
        int r = atomicAdd(done, 1);
        lastflag = (r == (int)gridDim.x - 1) ? 1 : 0;
    }
    __syncthreads();
    if (!lastflag) return;

    // ---------------- finalize (identical math to round-0 k4) ----------------
    double ce = 0.0;
    for (int t = tid; t < nPartial; t += 256) ce += (double)ce_partial[t];
    double p = 0.0, wsum = 0.0;
    for (int c = tid; c < CC; c += 256) {
        int P = P_arr[c], m = m_arr[c];
        double wgt = (double)weight[c];
        long long Nn = (long long)N - P;
        if (P > 0 && Nn > 0 && m > 0) {
            int gc = __hip_atomic_load(&g_cnt[c], __ATOMIC_RELAXED, __HIP_MEMORY_SCOPE_AGENT);
            int gs = __hip_atomic_load(&g_sum[c], __ATOMIC_RELAXED, __HIP_MEMORY_SCOPE_AGENT);
            double wm = (double)wm_arr[c];
            double S   = (double)gs + wm * (double)gc;
            double sub = 0.5 * (double)(m - 1) * (double)(m - 2) + wm * (double)(m - 1);
            double pc  = (S - sub) / ((double)Nn * (double)P);
            if (pc < 0.0) pc = 0.0;
            p += pc * wgt;
        }
        wsum += wgt;
    }
    r1[tid] = ce; r2[tid] = p; r3[tid] = wsum;
    __syncthreads();
    for (int off = 128; off; off >>= 1) {
        if (tid < off) {
            r1[tid] += r1[tid + off];
            r2[tid] += r2[tid + off];
            r3[tid] += r3[tid + off];
        }
        __syncthreads();
    }
    if (tid == 0) {
        double ce_loss = r1[0] / (double)N;
        double avg = r2[0] / (r3[0] * 0.05);           // MAX_PAUC = R1-R0 = 0.05
        avg = fmin(fmax(avg, 0.0), 1.0);
        out[0] = (float)(0.5 * ce_loss + 0.5 * (1.0 - avg * avg));
    }
}

extern "C" void kernel_launch(void* const* d_in, const int* in_sizes, int n_in,
                              void* d_out, int out_size, void* d_ws, size_t ws_size,
                              hipStream_t stream) {
    (void)n_in; (void)out_size;
    const float* pred    = (const float*)d_in[0];
    const int*   targets = (const int*)d_in[1];
    const float* weight  = (const float*)d_in[2];
    float* out = (float*)d_out;
    const int N = in_sizes[1];

    const int K1_BLOCKS = N / TILE;                    // 4096
    char* base = (char*)d_ws;
    size_t off = 0;
    auto take = [&](size_t bytes) { char* q = base + off; off += (bytes + 15) & ~(size_t)15; return q; };
    float* L_ws       = (float*)take((size_t)N * 4);
    float* pos_ws     = (float*)take((size_t)N * 4);
    float* ce_partial = (float*)take((size_t)K1_BLOCKS * 4);
    float* u          = (float*)take((size_t)CC * MAXM * 4);
    int*   m_arr      = (int*)take(CC * 4);
    int*   P_arr      = (int*)take(CC * 4);
    float* wm_arr     = (float*)take(CC * 4);
    int*   zero_blk   = (int*)take(304 * 4);           // cls_cnt|g_cnt|g_sum|list_cnt|done
    int*   cls_cnt  = zero_blk;
    int*   g_cnt    = zero_blk + CC;
    int*   g_sum    = zero_blk + 2 * CC;
    int*   list_cnt = zero_blk + 3 * CC;
    int*   done     = zero_blk + 3 * CC + 1;
    float* bucket     = (float*)take((size_t)CC * BUCKET * 4);   // 1.6 MB
    uint2* list       = (uint2*)(base + off);
    long long rem     = (long long)ws_size - (long long)off;
    int list_cap      = (rem > 0) ? (int)(rem / 8) : 0;          // expected need ~1.3M entries

    hipMemsetAsync(zero_blk, 0, 304 * 4, stream);

    k1_tile<<<K1_BLOCKS, 256, 0, stream>>>(pred, targets, weight, L_ws, pos_ws,
                                           ce_partial, N);
    k1b_scatter<<<256, 256, 0, stream>>>(targets, pos_ws, cls_cnt, bucket, N);
    k2_select<<<CC, 256, 0, stream>>>(bucket, cls_cnt, u, m_arr, P_arr, wm_arr);
    const int total4 = (int)((size_t)N * CC / 4);
    k3a_stream<<<K3AGRID, 256, 0, stream>>>((const float4*)pred, L_ws, u, m_arr,
                                            list, list_cnt, list_cap, g_cnt, g_sum, total4);
    k3b_rank_final<<<K3BGRID, 256, 0, stream>>>(list, list_cnt, list_cap, u, m_arr,
                                                P_arr, wm_arr, weight, ce_partial,
                                                K1_BLOCKS, g_cnt, g_sum, done, out, N);
}